// Round 1
// baseline (11856.689 us; speedup 1.0000x reference)
//
#include <hip/hip_runtime.h>

// Problem constants (fixed by the reference).
#define NSTEP 16384   // scan length (== B)
#define NCH   20      // independent chains (== T)
// hidden = 32, gates = 128 per layer.

__device__ __forceinline__ float rl(float v, int l) {
  return __builtin_bit_cast(float, __builtin_amdgcn_readlane(__builtin_bit_cast(int, v), l));
}
__device__ __forceinline__ float sigm(float x) { return 1.0f / (1.0f + __expf(-x)); }
__device__ __forceinline__ float tanh_(float x) {
  // 1 - 2/(1+e^{2x}); saturates correctly at +-1 (inf-safe).
  return 1.0f - 2.0f / (1.0f + __expf(2.0f * x));
}

// One block per chain n. 4 waves:
//  wave0: layer-1 full (recurrent + x input), writes h1 -> h1buf[t&1]
//  wave2/3: layer-2 input projection pin[t-1] = h1[t-1]@Wih2^T + b2  -> pinbuf
//  wave1: layer-2 recurrent + gates (t-2), stores ys2
__global__ __launch_bounds__(256, 1)
void lstm2_kernel(const float* __restrict__ x,
                  const float* __restrict__ Wih1, const float* __restrict__ Whh1,
                  const float* __restrict__ bih1, const float* __restrict__ bhh1,
                  const float* __restrict__ Wih2, const float* __restrict__ Whh2,
                  const float* __restrict__ bih2, const float* __restrict__ bhh2,
                  float* __restrict__ ys2)
{
  const int n    = blockIdx.x;
  const int tid  = threadIdx.x;
  const int wave = tid >> 6;
  const int lane = tid & 63;
  const int u    = lane & 31;
  const bool lower = (lane < 32);

  __shared__ __align__(16) float h1buf[2][32];
  __shared__ float pinbuf[2][128];

  float wA[32], wB[32];
  float wI0[6], wI1[6];
  float b0v = 0.f, b1v = 0.f;
  float hval = 0.f, cval = 0.f;
  float xv0 = 0.f, xv1 = 0.f, xv2 = 0.f, xv3 = 0.f, xv4 = 0.f, xv5 = 0.f;

  if (wave == 0) {
    const int j0 = lane, j1 = lane + 64;   // rows: i|f block and g|o block
#pragma unroll
    for (int k = 0; k < 32; ++k) { wA[k] = Whh1[j0 * 32 + k]; wB[k] = Whh1[j1 * 32 + k]; }
#pragma unroll
    for (int k = 0; k < 6; ++k)  { wI0[k] = Wih1[j0 * 6 + k]; wI1[k] = Wih1[j1 * 6 + k]; }
    b0v = bih1[j0] + bhh1[j0];
    b1v = bih1[j1] + bhh1[j1];
    const float* xp = x + (size_t)n * 6;   // t = 0
    xv0 = xp[0]; xv1 = xp[1]; xv2 = xp[2]; xv3 = xp[3]; xv4 = xp[4]; xv5 = xp[5];
  } else if (wave == 1) {
    const int j0 = lane, j1 = lane + 64;
#pragma unroll
    for (int k = 0; k < 32; ++k) { wA[k] = Whh2[j0 * 32 + k]; wB[k] = Whh2[j1 * 32 + k]; }
  } else {
    const int j = (wave - 2) * 64 + lane;  // 0..127
#pragma unroll
    for (int k = 0; k < 32; ++k) { wA[k] = Wih2[j * 32 + k]; }
    b0v = bih2[j] + bhh2[j];
  }

  for (int it = 0; it < NSTEP + 2; ++it) {
    __syncthreads();   // single barrier per step orders all LDS traffic

    if (wave == 0) {
      if (it < NSTEP) {
        float acc0 = b0v, acc1 = b1v;
        acc0 = fmaf(xv0, wI0[0], acc0); acc1 = fmaf(xv0, wI1[0], acc1);
        acc0 = fmaf(xv1, wI0[1], acc0); acc1 = fmaf(xv1, wI1[1], acc1);
        acc0 = fmaf(xv2, wI0[2], acc0); acc1 = fmaf(xv2, wI1[2], acc1);
        acc0 = fmaf(xv3, wI0[3], acc0); acc1 = fmaf(xv3, wI1[3], acc1);
        acc0 = fmaf(xv4, wI0[4], acc0); acc1 = fmaf(xv4, wI1[4], acc1);
        acc0 = fmaf(xv5, wI0[5], acc0); acc1 = fmaf(xv5, wI1[5], acc1);
#pragma unroll
        for (int k = 0; k < 32; ++k) {
          const float hk = rl(hval, k);        // broadcast h1[k] via v_readlane
          acc0 = fmaf(hk, wA[k], acc0);
          acc1 = fmaf(hk, wB[k], acc1);
        }
        if (it + 1 < NSTEP) {                  // prefetch next x (latency hidden)
          const float* xp = x + ((size_t)(it + 1) * NCH + n) * 6;
          xv0 = xp[0]; xv1 = xp[1]; xv2 = xp[2]; xv3 = xp[3]; xv4 = xp[4]; xv5 = xp[5];
        }
        // lower lane: (i,g); upper lane: (f,o) for the same unit u
        float Aval, Bval;
        if (lower) { Aval = sigm(acc0) * tanh_(acc1); Bval = 0.f; }
        else       { Aval = sigm(acc0); Bval = sigm(acc1); }
        const float rA = __shfl_xor(Aval, 32, 64);
        const float rB = __shfl_xor(Bval, 32, 64);
        const float fv = lower ? rA : Aval;
        const float ig = lower ? Aval : rA;
        const float ov = lower ? rB : Bval;
        cval = fmaf(fv, cval, ig);
        hval = ov * tanh_(cval);
        if (lower) h1buf[it & 1][u] = hval;
      }
    } else if (wave == 1) {
      if (it >= 2) {
        const int t = it - 2;
        float acc0 = pinbuf[t & 1][lane];
        float acc1 = pinbuf[t & 1][lane + 64];
#pragma unroll
        for (int k = 0; k < 32; ++k) {
          const float hk = rl(hval, k);        // broadcast h2[k]
          acc0 = fmaf(hk, wA[k], acc0);
          acc1 = fmaf(hk, wB[k], acc1);
        }
        float Aval, Bval;
        if (lower) { Aval = sigm(acc0) * tanh_(acc1); Bval = 0.f; }
        else       { Aval = sigm(acc0); Bval = sigm(acc1); }
        const float rA = __shfl_xor(Aval, 32, 64);
        const float rB = __shfl_xor(Bval, 32, 64);
        const float fv = lower ? rA : Aval;
        const float ig = lower ? Aval : rA;
        const float ov = lower ? rB : Bval;
        cval = fmaf(fv, cval, ig);
        hval = ov * tanh_(cval);
        if (lower) ys2[((size_t)t * NCH + n) * 32 + u] = hval;
      }
    } else {
      if (it >= 1 && it <= NSTEP) {
        const int t = it - 1;
        const float4* hb = (const float4*)h1buf[t & 1];   // broadcast reads
        float acc = b0v;
#pragma unroll
        for (int q = 0; q < 8; ++q) {
          const float4 hq = hb[q];
          acc = fmaf(hq.x, wA[4 * q + 0], acc);
          acc = fmaf(hq.y, wA[4 * q + 1], acc);
          acc = fmaf(hq.z, wA[4 * q + 2], acc);
          acc = fmaf(hq.w, wA[4 * q + 3], acc);
        }
        pinbuf[t & 1][(wave - 2) * 64 + lane] = acc;
      }
    }
  }
}

// MLP head: z(16384,640) -> relu(640->128) -> relu(128->32) -> 2.
// 16 rows per block, 128 threads.
__global__ __launch_bounds__(128, 1)
void head_kernel(const float* __restrict__ ys2,
                 const float* __restrict__ W1, const float* __restrict__ b1,
                 const float* __restrict__ W2, const float* __restrict__ b2,
                 const float* __restrict__ W3, const float* __restrict__ b3,
                 float* __restrict__ out)
{
  const int R = 16;
  const int b0 = blockIdx.x * R;
  const int tid = threadIdx.x;

  __shared__ __align__(16) float zl[R][640];
  __shared__ float z1[R][128];
  __shared__ float z2[R][32];

  // Stage 16 rows (coalesced float4).
  {
    const float4* src = (const float4*)(ys2 + (size_t)b0 * 640);
    float4* dst = (float4*)&zl[0][0];
    for (int i = tid; i < R * 160; i += 128) dst[i] = src[i];
  }
  __syncthreads();

  // Layer 1: thread = output column j (128), 16 rows.
  {
    float acc[R];
    const float bb = b1[tid];
#pragma unroll
    for (int r = 0; r < R; ++r) acc[r] = bb;
    for (int kk = 0; kk < 640; kk += 4) {
      const float4 w = *(const float4*)&W1[(size_t)tid * 640 + kk];
#pragma unroll
      for (int r = 0; r < R; ++r) {
        const float4 z4 = *(const float4*)&zl[r][kk];
        acc[r] = fmaf(w.x, z4.x, fmaf(w.y, z4.y, fmaf(w.z, z4.z, fmaf(w.w, z4.w, acc[r]))));
      }
    }
#pragma unroll
    for (int r = 0; r < R; ++r) z1[r][tid] = fmaxf(acc[r], 0.f);
  }
  __syncthreads();

  // Layer 2: jo = tid&31, row-group = tid>>5 handles rows rg+4q.
  {
    const int jo = tid & 31, rg = tid >> 5;
    float a2[4];
    const float bb = b2[jo];
#pragma unroll
    for (int q = 0; q < 4; ++q) a2[q] = bb;
    for (int k = 0; k < 128; ++k) {
      const float w = W2[jo * 128 + k];
#pragma unroll
      for (int q = 0; q < 4; ++q) a2[q] = fmaf(w, z1[rg + 4 * q][k], a2[q]);
    }
#pragma unroll
    for (int q = 0; q < 4; ++q) z2[rg + 4 * q][jo] = fmaxf(a2[q], 0.f);
  }
  __syncthreads();

  // Layer 3: 2 outputs x 16 rows, threads 0..31.
  if (tid < 32) {
    const int r = tid >> 1, jo = tid & 1;
    float a = b3[jo];
#pragma unroll
    for (int k = 0; k < 32; ++k) a = fmaf(W3[jo * 32 + k], z2[r][k], a);
    out[(size_t)(b0 + r) * 2 + jo] = a;
  }
}

extern "C" void kernel_launch(void* const* d_in, const int* in_sizes, int n_in,
                              void* d_out, int out_size, void* d_ws, size_t ws_size,
                              hipStream_t stream) {
  (void)in_sizes; (void)n_in; (void)out_size; (void)ws_size;
  const float* x    = (const float*)d_in[0];
  const float* Wih1 = (const float*)d_in[1];
  const float* Whh1 = (const float*)d_in[2];
  const float* bih1 = (const float*)d_in[3];
  const float* bhh1 = (const float*)d_in[4];
  const float* Wih2 = (const float*)d_in[5];
  const float* Whh2 = (const float*)d_in[6];
  const float* bih2 = (const float*)d_in[7];
  const float* bhh2 = (const float*)d_in[8];
  const float* W1   = (const float*)d_in[9];
  const float* b1   = (const float*)d_in[10];
  const float* W2   = (const float*)d_in[11];
  const float* b2   = (const float*)d_in[12];
  const float* W3   = (const float*)d_in[13];
  const float* b3   = (const float*)d_in[14];
  float* out = (float*)d_out;

  // ys2: (16384, 20, 32) fp32 = 41.9 MB in workspace.
  float* ys2 = (float*)d_ws;

  lstm2_kernel<<<NCH, 256, 0, stream>>>(x, Wih1, Whh1, bih1, bhh1,
                                        Wih2, Whh2, bih2, bhh2, ys2);
  head_kernel<<<NSTEP / 16, 128, 0, stream>>>(ys2, W1, b1, W2, b2, W3, b3, out);
}

// Round 2
// 9936.605 us; speedup vs baseline: 1.1932x; 1.1932x over previous
//
#include <hip/hip_runtime.h>

// Problem constants (fixed by the reference).
#define NSTEP 16384   // scan length (== B)
#define NCH   20      // independent chains (== T)
// hidden = 32, gates = 128 per layer.

// Raw barrier: order LDS (lgkmcnt) but leave global loads/stores in flight.
// __syncthreads() would drain vmcnt(0) every step -> exposes HBM latency.
#define BAR() asm volatile("s_waitcnt lgkmcnt(0)\n\ts_barrier" ::: "memory")

__device__ __forceinline__ float rl(float v, int l) {
  return __builtin_bit_cast(float, __builtin_amdgcn_readlane(__builtin_bit_cast(int, v), l));
}
__device__ __forceinline__ float sigm(float x) { return 1.0f / (1.0f + __expf(-x)); }
__device__ __forceinline__ float tanh_(float x) {
  // 1 - 2/(1+e^{2x}); saturates correctly at +-1 (inf-safe).
  return 1.0f - 2.0f / (1.0f + __expf(2.0f * x));
}
// Pin a loaded value into a VGPR; defeats rematerialization/spill of weights.
__device__ __forceinline__ void pin(float& v) { asm volatile("" : "+v"(v)); }

// One block per chain n. 4 waves:
//  wave0: layer-1 full (recurrent + x input), writes h1 -> h1buf[t&1]
//  wave2/3: layer-2 input projection pin[t] = h1[t]@Wih2^T + b2 -> pinbuf;
//           also stage x chunks (64 steps) from HBM into LDS.
//  wave1: layer-2 recurrent + gates (t = it-2), stores ys2
__global__ __launch_bounds__(256, 1)
void lstm2_kernel(const float* __restrict__ x,
                  const float* __restrict__ Wih1, const float* __restrict__ Whh1,
                  const float* __restrict__ bih1, const float* __restrict__ bhh1,
                  const float* __restrict__ Wih2, const float* __restrict__ Whh2,
                  const float* __restrict__ bih2, const float* __restrict__ bhh2,
                  float* __restrict__ ys2)
{
  const int n    = blockIdx.x;
  const int tid  = threadIdx.x;
  const int wave = tid >> 6;
  const int lane = tid & 63;
  const int u    = lane & 31;
  const bool lower = (lane < 32);

  __shared__ __align__(16) float h1buf[2][32];
  __shared__ __align__(16) float pinbuf[2][128];
  __shared__ __align__(16) float xbuf[2][64 * 6];   // x staged in 64-step chunks

  float wA[32], wB[32];
  float wI0[6], wI1[6];
  float b0v = 0.f, b1v = 0.f;
  float hval = 0.f, cval = 0.f;
  float sx0 = 0.f, sx1 = 0.f, sx2 = 0.f;   // staging regs (waves 2/3)

  // waves 2/3 staging geometry: 128 lanes cover 64*6=384 dwords, 3 per lane.
  const int L    = (wave - 2) * 64 + lane;   // 0..127 (valid for wave>=2)
  const int tloc = L >> 1;                   // local step 0..63
  const int i0   = (L & 1) * 3;              // feature offset 0 or 3 (never crosses a step)

  if (wave == 0) {
    const int j0 = lane, j1 = lane + 64;   // rows: i|f block and g|o block
#pragma unroll
    for (int k = 0; k < 32; ++k) {
      wA[k] = Whh1[j0 * 32 + k]; pin(wA[k]);
      wB[k] = Whh1[j1 * 32 + k]; pin(wB[k]);
    }
#pragma unroll
    for (int k = 0; k < 6; ++k)  { wI0[k] = Wih1[j0 * 6 + k]; wI1[k] = Wih1[j1 * 6 + k]; }
    b0v = bih1[j0] + bhh1[j0];
    b1v = bih1[j1] + bhh1[j1];
  } else if (wave == 1) {
    const int j0 = lane, j1 = lane + 64;
#pragma unroll
    for (int k = 0; k < 32; ++k) {
      wA[k] = Whh2[j0 * 32 + k]; pin(wA[k]);
      wB[k] = Whh2[j1 * 32 + k]; pin(wB[k]);
    }
  } else {
    const int j = L;                       // 0..127
#pragma unroll
    for (int k = 0; k < 32; ++k) { wA[k] = Wih2[j * 32 + k]; pin(wA[k]); }
    b0v = bih2[j] + bhh2[j];
    // Prologue: stage chunk 0 into xbuf[0].
    const float* xp = x + ((size_t)tloc * NCH + n) * 6 + i0;
    float a0 = xp[0], a1 = xp[1], a2 = xp[2];
    float* xd = &xbuf[0][L * 3];
    xd[0] = a0; xd[1] = a1; xd[2] = a2;
  }
  BAR();

  for (int it = 0; it < NSTEP + 2; ++it) {
    BAR();   // single barrier per step orders all LDS traffic (no vmcnt drain)

    if (wave == 0) {
      if (it < NSTEP) {
        const int t = it;
        // Issue x reads early (LDS broadcast); consume after the h-dot.
        const float* xb = &xbuf[(t >> 6) & 1][(t & 63) * 6];
        const float2 xa = *(const float2*)(xb + 0);
        const float2 xm = *(const float2*)(xb + 2);
        const float2 xc = *(const float2*)(xb + 4);
        float acc0 = b0v, acc1 = b1v;
#pragma unroll
        for (int k = 0; k < 32; ++k) {
          const float hk = rl(hval, k);        // broadcast h1[k] via v_readlane
          acc0 = fmaf(hk, wA[k], acc0);
          acc1 = fmaf(hk, wB[k], acc1);
        }
        acc0 = fmaf(xa.x, wI0[0], acc0); acc1 = fmaf(xa.x, wI1[0], acc1);
        acc0 = fmaf(xa.y, wI0[1], acc0); acc1 = fmaf(xa.y, wI1[1], acc1);
        acc0 = fmaf(xm.x, wI0[2], acc0); acc1 = fmaf(xm.x, wI1[2], acc1);
        acc0 = fmaf(xm.y, wI0[3], acc0); acc1 = fmaf(xm.y, wI1[3], acc1);
        acc0 = fmaf(xc.x, wI0[4], acc0); acc1 = fmaf(xc.x, wI1[4], acc1);
        acc0 = fmaf(xc.y, wI0[5], acc0); acc1 = fmaf(xc.y, wI1[5], acc1);
        // lower lane: (i,g); upper lane: (f,o) for the same unit u
        float Aval, Bval;
        if (lower) { Aval = sigm(acc0) * tanh_(acc1); Bval = 0.f; }
        else       { Aval = sigm(acc0); Bval = sigm(acc1); }
        const float rA = __shfl_xor(Aval, 32, 64);
        const float rB = __shfl_xor(Bval, 32, 64);
        const float fv = lower ? rA : Aval;
        const float ig = lower ? Aval : rA;
        const float ov = lower ? rB : Bval;
        cval = fmaf(fv, cval, ig);
        hval = ov * tanh_(cval);
        if (lower) h1buf[t & 1][u] = hval;
      }
    } else if (wave == 1) {
      if (it >= 2) {
        const int t = it - 2;
        // Issue pin reads first; h2-dot accumulates from 0 meanwhile.
        const float pin0 = pinbuf[t & 1][lane];
        const float pin1 = pinbuf[t & 1][lane + 64];
        float acc0 = 0.f, acc1 = 0.f;
#pragma unroll
        for (int k = 0; k < 32; ++k) {
          const float hk = rl(hval, k);        // broadcast h2[k]
          acc0 = fmaf(hk, wA[k], acc0);
          acc1 = fmaf(hk, wB[k], acc1);
        }
        acc0 += pin0;   // pin includes bih2+bhh2 and the h1@Wih2^T term
        acc1 += pin1;
        float Aval, Bval;
        if (lower) { Aval = sigm(acc0) * tanh_(acc1); Bval = 0.f; }
        else       { Aval = sigm(acc0); Bval = sigm(acc1); }
        const float rA = __shfl_xor(Aval, 32, 64);
        const float rB = __shfl_xor(Bval, 32, 64);
        const float fv = lower ? rA : Aval;
        const float ig = lower ? Aval : rA;
        const float ov = lower ? rB : Bval;
        cval = fmaf(fv, cval, ig);
        hval = ov * tanh_(cval);
        if (lower) ys2[((size_t)t * NCH + n) * 32 + u] = hval;
      }
    } else {
      // x staging: issue loads at chunk start, write to LDS 16 iters later
      // (vmcnt latency hidden; no stall).
      if ((it & 63) == 0) {
        const int cn = (it >> 6) + 1;
        if (cn < NSTEP / 64) {
          const float* xp = x + ((size_t)(cn * 64 + tloc) * NCH + n) * 6 + i0;
          sx0 = xp[0]; sx1 = xp[1]; sx2 = xp[2];
        }
      } else if ((it & 63) == 16) {
        const int cn = (it >> 6) + 1;
        if (cn < NSTEP / 64) {
          float* xd = &xbuf[cn & 1][L * 3];
          xd[0] = sx0; xd[1] = sx1; xd[2] = sx2;
        }
      }
      if (it >= 1 && it <= NSTEP) {
        const int t = it - 1;
        const float4* hb = (const float4*)h1buf[t & 1];   // broadcast reads
        float acc = b0v;
#pragma unroll
        for (int q = 0; q < 8; ++q) {
          const float4 hq = hb[q];
          acc = fmaf(hq.x, wA[4 * q + 0], acc);
          acc = fmaf(hq.y, wA[4 * q + 1], acc);
          acc = fmaf(hq.z, wA[4 * q + 2], acc);
          acc = fmaf(hq.w, wA[4 * q + 3], acc);
        }
        pinbuf[t & 1][L] = acc;
      }
    }
  }
}

// MLP head: z(16384,640) -> relu(640->128) -> relu(128->32) -> 2.
// 16 rows per block, 128 threads.
__global__ __launch_bounds__(128, 1)
void head_kernel(const float* __restrict__ ys2,
                 const float* __restrict__ W1, const float* __restrict__ b1,
                 const float* __restrict__ W2, const float* __restrict__ b2,
                 const float* __restrict__ W3, const float* __restrict__ b3,
                 float* __restrict__ out)
{
  const int R = 16;
  const int b0 = blockIdx.x * R;
  const int tid = threadIdx.x;

  __shared__ __align__(16) float zl[R][640];
  __shared__ float z1[R][128];
  __shared__ float z2[R][32];

  // Stage 16 rows (coalesced float4).
  {
    const float4* src = (const float4*)(ys2 + (size_t)b0 * 640);
    float4* dst = (float4*)&zl[0][0];
    for (int i = tid; i < R * 160; i += 128) dst[i] = src[i];
  }
  __syncthreads();

  // Layer 1: thread = output column j (128), 16 rows.
  {
    float acc[R];
    const float bb = b1[tid];
#pragma unroll
    for (int r = 0; r < R; ++r) acc[r] = bb;
    for (int kk = 0; kk < 640; kk += 4) {
      const float4 w = *(const float4*)&W1[(size_t)tid * 640 + kk];
#pragma unroll
      for (int r = 0; r < R; ++r) {
        const float4 z4 = *(const float4*)&zl[r][kk];
        acc[r] = fmaf(w.x, z4.x, fmaf(w.y, z4.y, fmaf(w.z, z4.z, fmaf(w.w, z4.w, acc[r]))));
      }
    }
#pragma unroll
    for (int r = 0; r < R; ++r) z1[r][tid] = fmaxf(acc[r], 0.f);
  }
  __syncthreads();

  // Layer 2: jo = tid&31, row-group = tid>>5 handles rows rg+4q.
  {
    const int jo = tid & 31, rg = tid >> 5;
    float a2[4];
    const float bb = b2[jo];
#pragma unroll
    for (int q = 0; q < 4; ++q) a2[q] = bb;
    for (int k = 0; k < 128; ++k) {
      const float w = W2[jo * 128 + k];
#pragma unroll
      for (int q = 0; q < 4; ++q) a2[q] = fmaf(w, z1[rg + 4 * q][k], a2[q]);
    }
#pragma unroll
    for (int q = 0; q < 4; ++q) z2[rg + 4 * q][jo] = fmaxf(a2[q], 0.f);
  }
  __syncthreads();

  // Layer 3: 2 outputs x 16 rows, threads 0..31.
  if (tid < 32) {
    const int r = tid >> 1, jo = tid & 1;
    float a = b3[jo];
#pragma unroll
    for (int k = 0; k < 32; ++k) a = fmaf(W3[jo * 32 + k], z2[r][k], a);
    out[(size_t)(b0 + r) * 2 + jo] = a;
  }
}

extern "C" void kernel_launch(void* const* d_in, const int* in_sizes, int n_in,
                              void* d_out, int out_size, void* d_ws, size_t ws_size,
                              hipStream_t stream) {
  (void)in_sizes; (void)n_in; (void)out_size; (void)ws_size;
  const float* x    = (const float*)d_in[0];
  const float* Wih1 = (const float*)d_in[1];
  const float* Whh1 = (const float*)d_in[2];
  const float* bih1 = (const float*)d_in[3];
  const float* bhh1 = (const float*)d_in[4];
  const float* Wih2 = (const float*)d_in[5];
  const float* Whh2 = (const float*)d_in[6];
  const float* bih2 = (const float*)d_in[7];
  const float* bhh2 = (const float*)d_in[8];
  const float* W1   = (const float*)d_in[9];
  const float* b1   = (const float*)d_in[10];
  const float* W2   = (const float*)d_in[11];
  const float* b2   = (const float*)d_in[12];
  const float* W3   = (const float*)d_in[13];
  const float* b3   = (const float*)d_in[14];
  float* out = (float*)d_out;

  // ys2: (16384, 20, 32) fp32 = 41.9 MB in workspace.
  float* ys2 = (float*)d_ws;

  lstm2_kernel<<<NCH, 256, 0, stream>>>(x, Wih1, Whh1, bih1, bhh1,
                                        Wih2, Whh2, bih2, bhh2, ys2);
  head_kernel<<<NSTEP / 16, 128, 0, stream>>>(ys2, W1, b1, W2, b2, W3, b3, out);
}

// Round 3
// 8797.065 us; speedup vs baseline: 1.3478x; 1.1295x over previous
//
#include <hip/hip_runtime.h>

// Problem constants (fixed by the reference).
#define NSTEP 16384   // scan length (== B)
#define NCH   20      // independent chains (== T)
// hidden = 32, gates = 128 per layer (torch order i,f,g,o).

// Raw barrier: order LDS (lgkmcnt) but leave global loads/stores in flight.
#define BAR() asm volatile("s_waitcnt lgkmcnt(0)\n\ts_barrier" ::: "memory")

__device__ __forceinline__ float rl(float v, int l) {
  return __builtin_bit_cast(float, __builtin_amdgcn_readlane(__builtin_bit_cast(int, v), l));
}
__device__ __forceinline__ float sigm(float x) { return 1.0f / (1.0f + __expf(-x)); }
__device__ __forceinline__ float tanh_(float x) {
  return 1.0f - 2.0f / (1.0f + __expf(2.0f * x));   // inf-safe
}

// 6 waves (384 threads), one block per chain n.
// KEY: every wave keeps exactly 32 weights in ONE unified w[32] array (single
// SSA live range shared by all role branches). Previous versions gave each
// role its own arrays; their live ranges interfered across the loop, summing
// to ~160 VGPRs -> the scheduler sank the weight loads into the loop (VGPR=60,
// ~60 global reloads per step). Unified storage keeps demand ~50/wave.
//
// Roles / software pipeline (iteration it, one barrier per iteration):
//  waves 0,1: layer-1. Update c1,h1 from gates(it-1), then compute
//             gates(it) = sigma/tanh(b + x(it)@Wih1^T + h1@Whh1^T) -> g1buf.
//             wave0 rows 0..63 (i|f), wave1 rows 64..127 (g|o).
//  waves 4,5: pin(tp=it-2) = h1(tp)@Wih2^T + b2 -> pinbuf; also stage x.
//  waves 2,3: layer-2. Update c2,h2 from gates2(it-4) (store ys2), then
//             gates2(tg=it-3) from pinbuf(tg) + h2@Whh2^T -> g2buf.
__global__ __launch_bounds__(384, 1)
void lstm2_kernel(const float* __restrict__ x,
                  const float* __restrict__ Wih1, const float* __restrict__ Whh1,
                  const float* __restrict__ bih1, const float* __restrict__ bhh1,
                  const float* __restrict__ Wih2, const float* __restrict__ Whh2,
                  const float* __restrict__ bih2, const float* __restrict__ bhh2,
                  float* __restrict__ ys2)
{
  const int n    = blockIdx.x;
  const int tid  = threadIdx.x;
  const int wave = tid >> 6;
  const int lane = tid & 63;
  const int u    = lane & 31;

  __shared__ __align__(16) float g1buf[2][128];    // [u*4 + gate] i,f,g~,o
  __shared__ __align__(16) float g2buf[2][128];
  __shared__ __align__(16) float h1buf[2][32];
  __shared__ __align__(16) float pinbuf[2][128];
  __shared__ __align__(16) float xbuf[2][64 * 6];  // x in 64-step chunks

  // ---- unified role setup: ONE weight array, ONE bias ----
  const int L    = (wave >= 4) ? (wave - 4) * 64 + lane : 0;  // proj row
  const int tloc = L >> 1;
  const int i0   = (L & 1) * 3;

  const float* wsrc;
  float bv = 0.f;
  if (wave < 2) {
    const int row = wave * 64 + lane;
    wsrc = Whh1 + row * 32;
    bv = bih1[row] + bhh1[row];
  } else if (wave < 4) {
    const int row = (wave - 2) * 64 + lane;
    wsrc = Whh2 + row * 32;
  } else {
    wsrc = Wih2 + L * 32;
    bv = bih2[L] + bhh2[L];
  }
  float w[32];
#pragma unroll
  for (int k = 0; k < 32; ++k) w[k] = wsrc[k];

  float wI[6] = {0.f, 0.f, 0.f, 0.f, 0.f, 0.f};
  if (wave < 2) {
    const int row = wave * 64 + lane;
#pragma unroll
    for (int k = 0; k < 6; ++k) wI[k] = Wih1[row * 6 + k];
  } else if (wave >= 4) {
    // prologue: stage x chunk 0
    const float* xp = x + ((size_t)tloc * NCH + n) * 6 + i0;
    const float a0 = xp[0], a1 = xp[1], a2 = xp[2];
    float* xd = &xbuf[0][L * 3];
    xd[0] = a0; xd[1] = a1; xd[2] = a2;
  }

  float hval = 0.f, cval = 0.f;
  float sx0 = 0.f, sx1 = 0.f, sx2 = 0.f;

  for (int it = 0; it < NSTEP + 4; ++it) {
    BAR();   // single barrier per step; vmcnt never drained in-loop

    if (wave < 2) {
      // ---- layer 1 ----
      if (it >= 1 && it <= NSTEP) {          // update c1,h1 from gates(it-1)
        const float4 gv = *(const float4*)&g1buf[(it - 1) & 1][u * 4];
        cval = fmaf(gv.y, cval, gv.x * gv.z);
        hval = gv.w * tanh_(cval);
        if (wave == 0 && lane < 32) h1buf[(it - 1) & 1][u] = hval;
      }
      if (it < NSTEP) {                      // gates(it) using fresh h1
        const float* xb = &xbuf[(it >> 6) & 1][(it & 63) * 6];
        const float2 xa = *(const float2*)(xb + 0);
        const float2 xm = *(const float2*)(xb + 2);
        const float2 xc = *(const float2*)(xb + 4);
        float xacc = bv;
        xacc = fmaf(xa.x, wI[0], xacc); xacc = fmaf(xa.y, wI[1], xacc);
        xacc = fmaf(xm.x, wI[2], xacc); xacc = fmaf(xm.y, wI[3], xacc);
        xacc = fmaf(xc.x, wI[4], xacc); xacc = fmaf(xc.y, wI[5], xacc);
        float acc0 = 0.f, acc1 = 0.f;
#pragma unroll
        for (int k = 0; k < 32; k += 2) {
          acc0 = fmaf(rl(hval, k),     w[k],     acc0);
          acc1 = fmaf(rl(hval, k + 1), w[k + 1], acc1);
        }
        const float acc = xacc + acc0 + acc1;
        const bool istanh = (wave == 1) && (lane < 32);   // g-gate rows 64..95
        const float v = istanh ? tanh_(acc) : sigm(acc);
        g1buf[it & 1][u * 4 + (wave * 2 + (lane >> 5))] = v;
      }
    } else if (wave < 4) {
      // ---- layer 2 ----
      if (it >= 4 && it <= NSTEP + 3) {      // update c2,h2 from gates2(it-4)
        const float4 gv = *(const float4*)&g2buf[(it - 4) & 1][u * 4];
        cval = fmaf(gv.y, cval, gv.x * gv.z);
        hval = gv.w * tanh_(cval);
        if (wave == 2 && lane < 32)
          ys2[((size_t)(it - 4) * NCH + n) * 32 + u] = hval;
      }
      if (it >= 3 && it <= NSTEP + 2) {      // gates2(tg) using fresh h2
        const int tg = it - 3;
        const float pinv = pinbuf[tg & 1][(wave - 2) * 64 + lane];
        float acc0 = 0.f, acc1 = 0.f;
#pragma unroll
        for (int k = 0; k < 32; k += 2) {
          acc0 = fmaf(rl(hval, k),     w[k],     acc0);
          acc1 = fmaf(rl(hval, k + 1), w[k + 1], acc1);
        }
        const float acc = pinv + acc0 + acc1;
        const bool istanh = (wave == 3) && (lane < 32);   // g-gate rows
        const float v = istanh ? tanh_(acc) : sigm(acc);
        g2buf[tg & 1][u * 4 + ((wave - 2) * 2 + (lane >> 5))] = v;
      }
    } else {
      // ---- projection + x staging ----
      if ((it & 63) == 0) {                  // issue next-chunk loads
        const int cn = (it >> 6) + 1;
        if (cn < NSTEP / 64) {
          const float* xp = x + ((size_t)(cn * 64 + tloc) * NCH + n) * 6 + i0;
          sx0 = xp[0]; sx1 = xp[1]; sx2 = xp[2];
        }
      } else if ((it & 63) == 16) {          // write 16 iters later (latency hidden)
        const int cn = (it >> 6) + 1;
        if (cn < NSTEP / 64) {
          float* xd = &xbuf[cn & 1][L * 3];
          xd[0] = sx0; xd[1] = sx1; xd[2] = sx2;
        }
      }
      if (it >= 2 && it <= NSTEP + 1) {      // pin(tp) = h1(tp)@Wih2^T + b2
        const int tp = it - 2;
        const float4* hb = (const float4*)h1buf[tp & 1];  // broadcast reads
        float a0 = bv, a1 = 0.f;
#pragma unroll
        for (int q = 0; q < 8; q += 2) {
          const float4 h0 = hb[q], h1v = hb[q + 1];
          a0 = fmaf(h0.x,  w[4*q + 0], a0); a1 = fmaf(h0.y,  w[4*q + 1], a1);
          a0 = fmaf(h0.z,  w[4*q + 2], a0); a1 = fmaf(h0.w,  w[4*q + 3], a1);
          a0 = fmaf(h1v.x, w[4*q + 4], a0); a1 = fmaf(h1v.y, w[4*q + 5], a1);
          a0 = fmaf(h1v.z, w[4*q + 6], a0); a1 = fmaf(h1v.w, w[4*q + 7], a1);
        }
        pinbuf[tp & 1][L] = a0 + a1;
      }
    }
  }
}

// MLP head: z(16384,640) -> relu(640->128) -> relu(128->32) -> 2.
__global__ __launch_bounds__(128, 1)
void head_kernel(const float* __restrict__ ys2,
                 const float* __restrict__ W1, const float* __restrict__ b1,
                 const float* __restrict__ W2, const float* __restrict__ b2,
                 const float* __restrict__ W3, const float* __restrict__ b3,
                 float* __restrict__ out)
{
  const int R = 16;
  const int b0 = blockIdx.x * R;
  const int tid = threadIdx.x;

  __shared__ __align__(16) float zl[R][640];
  __shared__ float z1[R][128];
  __shared__ float z2[R][32];

  {
    const float4* src = (const float4*)(ys2 + (size_t)b0 * 640);
    float4* dst = (float4*)&zl[0][0];
    for (int i = tid; i < R * 160; i += 128) dst[i] = src[i];
  }
  __syncthreads();

  {
    float acc[R];
    const float bb = b1[tid];
#pragma unroll
    for (int r = 0; r < R; ++r) acc[r] = bb;
    for (int kk = 0; kk < 640; kk += 4) {
      const float4 w = *(const float4*)&W1[(size_t)tid * 640 + kk];
#pragma unroll
      for (int r = 0; r < R; ++r) {
        const float4 z4 = *(const float4*)&zl[r][kk];
        acc[r] = fmaf(w.x, z4.x, fmaf(w.y, z4.y, fmaf(w.z, z4.z, fmaf(w.w, z4.w, acc[r]))));
      }
    }
#pragma unroll
    for (int r = 0; r < R; ++r) z1[r][tid] = fmaxf(acc[r], 0.f);
  }
  __syncthreads();

  {
    const int jo = tid & 31, rg = tid >> 5;
    float a2[4];
    const float bb = b2[jo];
#pragma unroll
    for (int q = 0; q < 4; ++q) a2[q] = bb;
    for (int k = 0; k < 128; ++k) {
      const float w = W2[jo * 128 + k];
#pragma unroll
      for (int q = 0; q < 4; ++q) a2[q] = fmaf(w, z1[rg + 4 * q][k], a2[q]);
    }
#pragma unroll
    for (int q = 0; q < 4; ++q) z2[rg + 4 * q][jo] = fmaxf(a2[q], 0.f);
  }
  __syncthreads();

  if (tid < 32) {
    const int r = tid >> 1, jo = tid & 1;
    float a = b3[jo];
#pragma unroll
    for (int k = 0; k < 32; ++k) a = fmaf(W3[jo * 32 + k], z2[r][k], a);
    out[(size_t)(b0 + r) * 2 + jo] = a;
  }
}

extern "C" void kernel_launch(void* const* d_in, const int* in_sizes, int n_in,
                              void* d_out, int out_size, void* d_ws, size_t ws_size,
                              hipStream_t stream) {
  (void)in_sizes; (void)n_in; (void)out_size; (void)ws_size;
  const float* x    = (const float*)d_in[0];
  const float* Wih1 = (const float*)d_in[1];
  const float* Whh1 = (const float*)d_in[2];
  const float* bih1 = (const float*)d_in[3];
  const float* bhh1 = (const float*)d_in[4];
  const float* Wih2 = (const float*)d_in[5];
  const float* Whh2 = (const float*)d_in[6];
  const float* bih2 = (const float*)d_in[7];
  const float* bhh2 = (const float*)d_in[8];
  const float* W1   = (const float*)d_in[9];
  const float* b1   = (const float*)d_in[10];
  const float* W2   = (const float*)d_in[11];
  const float* b2   = (const float*)d_in[12];
  const float* W3   = (const float*)d_in[13];
  const float* b3   = (const float*)d_in[14];
  float* out = (float*)d_out;

  float* ys2 = (float*)d_ws;   // (16384, 20, 32) fp32 = 41.9 MB

  lstm2_kernel<<<NCH, 384, 0, stream>>>(x, Wih1, Whh1, bih1, bhh1,
                                        Wih2, Whh2, bih2, bhh2, ys2);
  head_kernel<<<NSTEP / 16, 128, 0, stream>>>(ys2, W1, b1, W2, b2, W3, b3, out);
}